// Round 8
// baseline (716.398 us; speedup 1.0000x reference)
//
#include <hip/hip_runtime.h>
#include <math.h>

#define NN 50000
#define NE 800000
#define GG 50

typedef unsigned int u32;
typedef unsigned short u16;
typedef float v2f __attribute__((ext_vector_type(2)));
typedef short bf16x8 __attribute__((ext_vector_type(8)));
typedef float f32x4 __attribute__((ext_vector_type(4)));

__device__ __forceinline__ float uaf(u32 x) { return __uint_as_float(x); }

__device__ __forceinline__ u32 bfpack2(float x, float y) {
    u32 a = __float_as_uint(x), b = __float_as_uint(y);
    a = (a + 0x7fffu + ((a >> 16) & 1u)) >> 16;
    b = (b + 0x7fffu + ((b >> 16) & 1u)) & 0xffff0000u;
    return b | a;
}
__device__ __forceinline__ u16 bf16of(float x) {
    u32 a = __float_as_uint(x);
    return (u16)((a + 0x7fffu + ((a >> 16) & 1u)) >> 16);
}

// DPP-based partial reductions (VALU, no LDS pipe). ctrl must be an immediate.
template <int CTRL>
__device__ __forceinline__ float dpp_add(float v) {
    int t = __builtin_amdgcn_update_dpp(0, __float_as_int(v), CTRL, 0xf, 0xf, true);
    return v + __int_as_float(t);
}
__device__ __forceinline__ float swz_xor16_add(float v) {
    int t = __builtin_amdgcn_ds_swizzle(__float_as_int(v), 0x401F);
    return v + __int_as_float(t);
}
__device__ __forceinline__ float row4_total(float v) {
    return __int_as_float(__builtin_amdgcn_readlane(__float_as_int(v), 0))
         + __int_as_float(__builtin_amdgcn_readlane(__float_as_int(v), 16))
         + __int_as_float(__builtin_amdgcn_readlane(__float_as_int(v), 32))
         + __int_as_float(__builtin_amdgcn_readlane(__float_as_int(v), 48));
}
#define RED4_STAGES(q)  do {                                                    \
    _Pragma("unroll") for (int j = 0; j < 4; ++j) q[j] = dpp_add<0xB1>(q[j]);  \
    _Pragma("unroll") for (int j = 0; j < 4; ++j) q[j] = dpp_add<0x4E>(q[j]);  \
    _Pragma("unroll") for (int j = 0; j < 4; ++j) q[j] = dpp_add<0x141>(q[j]); \
    _Pragma("unroll") for (int j = 0; j < 4; ++j) q[j] = dpp_add<0x140>(q[j]); \
} while (0)

// ---------------- utility ----------------
__global__ void zero_u32_kernel(u32* __restrict__ p, int n) {
    int i = blockIdx.x * 256 + threadIdx.x;
    if (i < n) p[i] = 0u;
}

// fp32 pairs -> packed bf16 u32 (generic)
__global__ void pack_pairs_kernel(const float* __restrict__ src, u32* __restrict__ dst, int npairs) {
    int i = blockIdx.x * 256 + threadIdx.x;
    if (i < npairs) {
        float2 v = *(const float2*)(src + (size_t)i * 2);
        dst[i] = bfpack2(v.x, v.y);
    }
}

// 3x W [128][M] fp32 -> Wt [3*M][64] packed bf16 k-pairs (transposed)
__global__ void wpack3_kernel(const float* __restrict__ W0, const float* __restrict__ W1,
                              const float* __restrict__ W2, u32* __restrict__ Wt, int M) {
    int i = blockIdx.x * 256 + threadIdx.x;
    int per = M * 64;
    if (i < 3 * per) {
        int mat = i / per;
        int r = i - mat * per;
        const float* W = (mat == 0) ? W0 : (mat == 1) ? W1 : W2;
        int col = r >> 6, c = r & 63;
        Wt[i] = bfpack2(W[(size_t)(2 * c) * M + col], W[(size_t)(2 * c + 1) * M + col]);
    }
}

// ---------------- CSR build (by dst) ----------------
__global__ void count_edges_kernel(const int* __restrict__ ei, u32* __restrict__ counts) {
    int e = blockIdx.x * 256 + threadIdx.x;
    if (e < NE) atomicAdd(&counts[ei[NE + e]], 1u);
}

__global__ void scan_part1_kernel(const u32* __restrict__ counts, u32* __restrict__ bsums) {
    __shared__ u32 ls[256];
    int t = threadIdx.x;
    int base = blockIdx.x * 1024 + t * 4;
    u32 s = 0;
#pragma unroll
    for (int j = 0; j < 4; ++j) { int idx = base + j; if (idx < NN) s += counts[idx]; }
    ls[t] = s;
    __syncthreads();
    for (int off = 128; off > 0; off >>= 1) {
        if (t < off) ls[t] += ls[t + off];
        __syncthreads();
    }
    if (t == 0) bsums[blockIdx.x] = ls[0];
}

__global__ void scan_offsets_kernel(u32* bsums, int nb) {
    int lane = threadIdx.x;
    u32 v = (lane < nb) ? bsums[lane] : 0u;
#pragma unroll
    for (int off = 1; off < 64; off <<= 1) {
        u32 t = __shfl_up(v, off, 64);
        if (lane >= off) v += t;
    }
    u32 ex = __shfl_up(v, 1, 64);
    if (lane == 0) ex = 0u;
    if (lane < nb) bsums[lane] = ex;
}

__global__ void scan_final_kernel(const u32* __restrict__ counts, const u32* __restrict__ bsums,
                                  int* __restrict__ rowptr) {
    __shared__ u32 ls[256];
    int t = threadIdx.x;
    int base = blockIdx.x * 1024 + t * 4;
    u32 c[4];
    u32 s = 0;
#pragma unroll
    for (int j = 0; j < 4; ++j) { int idx = base + j; c[j] = (idx < NN) ? counts[idx] : 0u; s += c[j]; }
    ls[t] = s;
    __syncthreads();
    for (int off = 1; off < 256; off <<= 1) {
        u32 add = (t >= off) ? ls[t - off] : 0u;
        __syncthreads();
        ls[t] += add;
        __syncthreads();
    }
    u32 run = ls[t] - s + bsums[blockIdx.x];
#pragma unroll
    for (int j = 0; j < 4; ++j) { int idx = base + j; if (idx < NN) { rowptr[idx] = (int)run; } run += c[j]; }
    if (blockIdx.x == 0 && t == 0) rowptr[NN] = NE;
}

__global__ void scatter_edges_kernel(const int* __restrict__ ei, const int* __restrict__ rowptr,
                                     u32* __restrict__ cursors, int2* __restrict__ pairs) {
    int e = blockIdx.x * 256 + threadIdx.x;
    if (e < NE) {
        int src = ei[e];
        int d = ei[NE + e];
        u32 pos = atomicAdd(&cursors[d], 1u);
        pairs[rowptr[d] + pos] = make_int2(src, e);
    }
}

// ---------------- MFMA GEMM: [n,128]bf16 @ Wt -> 3 mats ----------------
__global__ __launch_bounds__(256) void gemm_mfma_kernel(
    const u32* __restrict__ Xp, const u32* __restrict__ Wt,
    u16* __restrict__ out0, float* __restrict__ out1, float* __restrict__ out2,
    const float* __restrict__ b0, const float* __restrict__ b1, const float* __restrict__ b2,
    int n, int nbPerMat, int outStride)
{
    __shared__ __align__(16) u32 Xs[64 * 68];
    __shared__ __align__(16) u32 Ws[64 * 68];
    int t = threadIdx.x;
    int row0 = blockIdx.x * 64;
    int nb = blockIdx.y;
    int mat = nb / nbPerMat;
    int col0 = (nb - mat * nbPerMat) * 64;
    int gcol0 = nb * 64;

#pragma unroll
    for (int i = 0; i < 16; ++i) {
        int flat = t + 256 * i;
        int r = flat >> 6, c = flat & 63;
        int gr = row0 + r;
        u32 v = (gr < n) ? Xp[(size_t)gr * 64 + c] : 0u;
        Xs[r * 68 + c] = v;
    }
#pragma unroll
    for (int i = 0; i < 16; ++i) {
        int flat = t + 256 * i;
        int cc = flat >> 6, c = flat & 63;
        Ws[cc * 68 + c] = Wt[(size_t)(gcol0 + cc) * 64 + c];
    }
    __syncthreads();

    int w = t >> 6, lane = t & 63;
    int l15 = lane & 15, quad = lane >> 4;
    f32x4 acc[4] = {};
#pragma unroll
    for (int kk = 0; kk < 4; ++kk) {
        bf16x8 af = *(const bf16x8*)&Xs[(w * 16 + l15) * 68 + kk * 16 + quad * 4];
#pragma unroll
        for (int j = 0; j < 4; ++j) {
            bf16x8 bf = *(const bf16x8*)&Ws[(j * 16 + l15) * 68 + kk * 16 + quad * 4];
            acc[j] = __builtin_amdgcn_mfma_f32_16x16x32_bf16(af, bf, acc[j], 0, 0, 0);
        }
    }

    const float* bp = (mat == 0) ? b0 : (mat == 1) ? b1 : b2;
#pragma unroll
    for (int j = 0; j < 4; ++j) {
        int col = col0 + j * 16 + l15;
        float bb = bp[col];
#pragma unroll
        for (int r = 0; r < 4; ++r) {
            int grow = row0 + w * 16 + quad * 4 + r;
            if (grow < n) {
                float v = acc[j][r] + bb;
                if (mat == 0) {
                    out0[(size_t)grow * outStride + col] = bf16of(v);
                } else if (mat == 1) {
                    out1[(size_t)grow * outStride + col] = v;
                } else {
                    out2[(size_t)grow * outStride + col] = v;
                }
            }
        }
    }
}

// ---------------- fused GATv2 layer 1 (H=2, C=64): bf16 xl, fp32 scalar ea, DPP reduce ----------------
__global__ __launch_bounds__(256) void gat1_fused_kernel(
    const u32* __restrict__ xlp, const float* __restrict__ xr,
    const float* __restrict__ ea, const int2* __restrict__ pairs,
    const int* __restrict__ rowptr, const float* __restrict__ We,
    const float* __restrict__ att, const float* __restrict__ bias,
    float* __restrict__ out)
{
    int lane = threadIdx.x & 63;
    int d = (blockIdx.x * 256 + threadIdx.x) >> 6;
    if (d >= NN) return;
    int du = __builtin_amdgcn_readfirstlane(d);
    int beg = rowptr[du], end = rowptr[du + 1];
    int c0 = lane * 2;
    v2f w[16];
#pragma unroll
    for (int k = 0; k < 16; ++k) {
        float2 t2 = *(const float2*)(We + k * 128 + c0);
        w[k] = (v2f){t2.x, t2.y};
    }
    float a0 = att[c0], a1 = att[c0 + 1];
    float2 bt = *(const float2*)(bias + c0);
    float2 xq = *(const float2*)(xr + (size_t)du * 128 + c0);
    v2f xrv = {xq.x, xq.y};

    float m = -INFINITY, s = 0.f;
    v2f acc = {0.f, 0.f};

    int cnt = (end - beg) >> 2;
    int2 pA[4]; u32 xA[4];
    int2 pB[4]; u32 xB[4];

#define G1_LOAD(P, X, base_) do {                                              \
    _Pragma("unroll")                                                          \
    for (int j = 0; j < 4; ++j) P[j] = pairs[(base_) + j];                     \
    _Pragma("unroll")                                                          \
    for (int j = 0; j < 4; ++j) X[j] = xlp[(size_t)P[j].x * 64 + lane];        \
} while (0)

#define G1_PROC(P, X) do {                                                     \
    float q[4]; v2f xv[4];                                                     \
    _Pragma("unroll")                                                          \
    for (int j = 0; j < 4; ++j) {                                              \
        const float* er_ = ea + (size_t)P[j].y * 16;   /* wave-uniform */      \
        v2f e = {0.f, 0.f};                                                    \
        _Pragma("unroll")                                                      \
        for (int k = 0; k < 16; ++k) e = w[k] * er_[k] + e;  /* pk_fma, sgpr */\
        u32 px = X[j];                                                         \
        xv[j] = (v2f){uaf(px << 16), uaf(px & 0xffff0000u)};                   \
        v2f mm = xv[j] + xrv + e;                                              \
        float lx = fmaxf(mm.x, 0.2f * mm.x);                                   \
        float ly = fmaxf(mm.y, 0.2f * mm.y);                                   \
        q[j] = fmaf(lx, a0, ly * a1);                                          \
    }                                                                          \
    RED4_STAGES(q);                                                            \
    _Pragma("unroll")                                                          \
    for (int j = 0; j < 4; ++j) q[j] = swz_xor16_add(q[j]);                    \
    float nm = fmaxf(fmaxf(fmaxf(q[0], q[1]), fmaxf(q[2], q[3])), m);          \
    float r = __expf(m - nm);                                                  \
    float w0 = __expf(q[0] - nm), w1 = __expf(q[1] - nm);                      \
    float w2 = __expf(q[2] - nm), w3 = __expf(q[3] - nm);                      \
    s = fmaf(s, r, (w0 + w1) + (w2 + w3));                                     \
    acc = acc * r + (xv[0] * w0 + xv[1] * w1) + (xv[2] * w2 + xv[3] * w3);     \
    m = nm;                                                                    \
} while (0)

    if (cnt > 0) {
        G1_LOAD(pA, xA, beg);
        int g = 0;
        for (; g + 2 <= cnt; g += 2) {
            G1_LOAD(pB, xB, beg + (g + 1) * 4);
            G1_PROC(pA, xA);
            if (g + 2 < cnt) G1_LOAD(pA, xA, beg + (g + 2) * 4);
            G1_PROC(pB, xB);
        }
        if (g < cnt) G1_PROC(pA, xA);
    }
#undef G1_LOAD
#undef G1_PROC
    for (int i = beg + cnt * 4; i < end; ++i) {
        int2 pr = pairs[i];
        const float* er = ea + (size_t)pr.y * 16;
        u32 px = xlp[(size_t)pr.x * 64 + lane];
        v2f xv = {uaf(px << 16), uaf(px & 0xffff0000u)};
        v2f e = {0.f, 0.f};
#pragma unroll
        for (int k = 0; k < 16; ++k) e = w[k] * er[k] + e;
        v2f mm = xv + xrv + e;
        float lx = fmaxf(mm.x, 0.2f * mm.x);
        float ly = fmaxf(mm.y, 0.2f * mm.y);
        float p = fmaf(lx, a0, ly * a1);
        p = dpp_add<0xB1>(p);
        p = dpp_add<0x4E>(p);
        p = dpp_add<0x141>(p);
        p = dpp_add<0x140>(p);
        p = swz_xor16_add(p);
        float nm = fmaxf(m, p);
        float r = __expf(m - nm), ww = __expf(p - nm);
        s = fmaf(s, r, ww);
        acc = acc * r + xv * ww;
        m = nm;
    }
    float inv = 1.f / (s + 1e-16f);
    float2 o;
    o.x = fmaf(acc.x, inv, bt.x);
    o.y = fmaf(acc.y, inv, bt.y);
    *(float2*)(out + (size_t)d * 128 + c0) = o;
}

// ---------------- fused GATv2 layer 2 (H=1, C=64): bf16 xl, fp32 k-pair ea, DPP reduce ----------------
__global__ __launch_bounds__(256) void gat2_fused_kernel(
    const u16* __restrict__ xlp, const float* __restrict__ xr,
    const float* __restrict__ ea, const int2* __restrict__ pairs,
    const int* __restrict__ rowptr, const float* __restrict__ We,
    const float* __restrict__ att, const float* __restrict__ bias,
    float* __restrict__ out)
{
    int lane = threadIdx.x & 63;
    int d = (blockIdx.x * 256 + threadIdx.x) >> 6;
    if (d >= NN) return;
    int du = __builtin_amdgcn_readfirstlane(d);
    int beg = rowptr[du], end = rowptr[du + 1];
    v2f wp[8];   // k-pairs of We for this lane's channel
#pragma unroll
    for (int k = 0; k < 8; ++k)
        wp[k] = (v2f){We[(2 * k) * 64 + lane], We[(2 * k + 1) * 64 + lane]};
    float a0 = att[lane];
    float bb = bias[lane];
    float xrv = xr[(size_t)du * 64 + lane];

    float m = -INFINITY, s = 0.f, acc = 0.f;

    int cnt = (end - beg) >> 2;
    int2 pA[4]; float xA[4];
    int2 pB[4]; float xB[4];

#define G2_LOAD(P, X, base_) do {                                              \
    _Pragma("unroll")                                                          \
    for (int j = 0; j < 4; ++j) P[j] = pairs[(base_) + j];                     \
    _Pragma("unroll")                                                          \
    for (int j = 0; j < 4; ++j)                                                \
        X[j] = uaf((u32)xlp[(size_t)P[j].x * 64 + lane] << 16);                \
} while (0)

#define G2_PROC(P, X) do {                                                     \
    float q[4];                                                                \
    _Pragma("unroll")                                                          \
    for (int j = 0; j < 4; ++j) {                                              \
        const v2f* er_ = (const v2f*)(ea + (size_t)P[j].y * 16);               \
        v2f ev = {0.f, 0.f};                                                   \
        _Pragma("unroll")                                                      \
        for (int k = 0; k < 8; ++k) ev = wp[k] * er_[k] + ev;                  \
        float mm = X[j] + xrv + (ev.x + ev.y);                                 \
        mm = fmaxf(mm, 0.2f * mm);                                             \
        q[j] = mm * a0;                                                        \
    }                                                                          \
    RED4_STAGES(q);                                                            \
    _Pragma("unroll")                                                          \
    for (int j = 0; j < 4; ++j) q[j] = row4_total(q[j]);                       \
    float nm = fmaxf(fmaxf(fmaxf(q[0], q[1]), fmaxf(q[2], q[3])), m);          \
    float r = __expf(m - nm);                                                  \
    float w0 = __expf(q[0] - nm), w1 = __expf(q[1] - nm);                      \
    float w2 = __expf(q[2] - nm), w3 = __expf(q[3] - nm);                      \
    s = fmaf(s, r, (w0 + w1) + (w2 + w3));                                     \
    acc = fmaf(acc, r, fmaf(w0, X[0], fmaf(w1, X[1], fmaf(w2, X[2], w3 * X[3])))); \
    m = nm;                                                                    \
} while (0)

    if (cnt > 0) {
        G2_LOAD(pA, xA, beg);
        int g = 0;
        for (; g + 2 <= cnt; g += 2) {
            G2_LOAD(pB, xB, beg + (g + 1) * 4);
            G2_PROC(pA, xA);
            if (g + 2 < cnt) G2_LOAD(pA, xA, beg + (g + 2) * 4);
            G2_PROC(pB, xB);
        }
        if (g < cnt) G2_PROC(pA, xA);
    }
#undef G2_LOAD
#undef G2_PROC
    for (int i = beg + cnt * 4; i < end; ++i) {
        int2 pr = pairs[i];
        const v2f* er = (const v2f*)(ea + (size_t)pr.y * 16);
        float xv = uaf((u32)xlp[(size_t)pr.x * 64 + lane] << 16);
        v2f ev = {0.f, 0.f};
#pragma unroll
        for (int k = 0; k < 8; ++k) ev = wp[k] * er[k] + ev;
        float mm = xv + xrv + (ev.x + ev.y);
        mm = fmaxf(mm, 0.2f * mm);
        float p = mm * a0;
        p = dpp_add<0xB1>(p);
        p = dpp_add<0x4E>(p);
        p = dpp_add<0x141>(p);
        p = dpp_add<0x140>(p);
        p = row4_total(p);
        float nm = fmaxf(m, p);
        float r = __expf(m - nm), ww = __expf(p - nm);
        s = fmaf(s, r, ww);
        acc = fmaf(acc, r, ww * xv);
        m = nm;
    }
    out[(size_t)d * 64 + lane] = acc / (s + 1e-16f) + bb;
}

// ---------------- batch-norm stats ----------------
template <int C>
__global__ __launch_bounds__(256) void bn_stats_kernel(const float* __restrict__ h, float* __restrict__ stats) {
    const int SUB = 256 / C;
    int t = threadIdx.x;
    int c = t & (C - 1);
    int rs = t / C;
    int r0 = blockIdx.x * 512;
    int r1 = min(NN, r0 + 512);
    float s = 0.f, s2 = 0.f;
    for (int r = r0 + rs; r < r1; r += SUB) {
        float v = h[(size_t)r * C + c];
        s += v; s2 = fmaf(v, v, s2);
    }
    __shared__ float ls[256], ls2[256];
    ls[t] = s; ls2[t] = s2;
    __syncthreads();
    if (rs == 0) {
        for (int j = 1; j < SUB; ++j) { s += ls[j * C + c]; s2 += ls2[j * C + c]; }
        atomicAdd(&stats[c], s);
        atomicAdd(&stats[C + c], s2);
    }
}

// ---------------- BN apply + skip + ELU -> packed bf16 (layer-1 out = layer-2 GEMM input) ----------------
__global__ __launch_bounds__(256) void bn_apply_pack_kernel(
    const float* __restrict__ h, const float* __restrict__ xp,
    const float* __restrict__ stats, const float* __restrict__ g,
    const float* __restrict__ b, u32* __restrict__ outp)
{
    int i = blockIdx.x * 256 + threadIdx.x;
    if (i >= NN * 64) return;
    int c2 = i & 63;
    int row = i >> 6;
    int c = c2 * 2;
    float2 hv = *(const float2*)(h + (size_t)row * 128 + c);
    float2 xv = *(const float2*)(xp + (size_t)row * 128 + c);
    float mu0 = stats[c] * (1.f / NN);
    float var0 = stats[128 + c] * (1.f / NN) - mu0 * mu0;
    float v0 = (hv.x - mu0) * rsqrtf(var0 + 1e-5f) * g[c] + b[c] + xv.x;
    v0 = (v0 > 0.f) ? v0 : expm1f(v0);
    float mu1 = stats[c + 1] * (1.f / NN);
    float var1 = stats[129 + c] * (1.f / NN) - mu1 * mu1;
    float v1 = (hv.y - mu1) * rsqrtf(var1 + 1e-5f) * g[c + 1] + b[c + 1] + xv.y;
    v1 = (v1 > 0.f) ? v1 : expm1f(v1);
    outp[i] = bfpack2(v0, v1);
}

// ---------------- BN apply + skip + ELU (fp32 out, final layer) ----------------
template <int C>
__global__ __launch_bounds__(256) void bn_apply_kernel(
    const float* __restrict__ h, const float* __restrict__ xp,
    const float* __restrict__ stats, const float* __restrict__ g,
    const float* __restrict__ b, float* __restrict__ outp)
{
    int i = blockIdx.x * 256 + threadIdx.x;
    if (i >= NN * C) return;
    int c = i & (C - 1);
    float mu = stats[c] * (1.f / NN);
    float var = stats[C + c] * (1.f / NN) - mu * mu;
    float sc = rsqrtf(var + 1e-5f) * g[c];
    float v = (h[i] - mu) * sc + b[c] + xp[i];
    outp[i] = (v > 0.f) ? v : expm1f(v);
}

// ---------------- per-graph mean/max pooling ----------------
__global__ __launch_bounds__(256) void pool_kernel(
    const float* __restrict__ h2, const int* __restrict__ batch, float* __restrict__ pooled)
{
    int g = blockIdx.x;
    int t = threadIdx.x;
    int lane = t & 63, w = t >> 6;
    int lo = 0, hi = NN;
    while (lo < hi) { int mid = (lo + hi) >> 1; if (batch[mid] < g) lo = mid + 1; else hi = mid; }
    int s0 = lo;
    hi = NN;
    while (lo < hi) { int mid = (lo + hi) >> 1; if (batch[mid] < g + 1) lo = mid + 1; else hi = mid; }
    int e0 = lo;
    float sum = 0.f, mx = -INFINITY;
    for (int r = s0 + w; r < e0; r += 4) {
        float v = h2[(size_t)r * 64 + lane];
        sum += v; mx = fmaxf(mx, v);
    }
    __shared__ float lsum[256], lmax[256];
    lsum[t] = sum; lmax[t] = mx;
    __syncthreads();
    if (w == 0) {
        for (int j = 1; j < 4; ++j) { sum += lsum[j * 64 + lane]; mx = fmaxf(mx, lmax[j * 64 + lane]); }
        float cnt = (float)(e0 - s0);
        pooled[g * 128 + lane] = sum / fmaxf(cnt, 1.f);
        pooled[g * 128 + 64 + lane] = mx;
    }
}

// ---------------- classifier ----------------
__global__ void classifier_kernel(const float* __restrict__ pooled, const float* __restrict__ w,
                                  const float* __restrict__ b, float* __restrict__ outp)
{
    int t = threadIdx.x;
    if (t < 100) {
        int g = t >> 1, c = t & 1;
        float acc = b[c];
        for (int k = 0; k < 128; ++k) acc = fmaf(pooled[g * 128 + k], w[k * 2 + c], acc);
        outp[t] = acc;
    }
}

extern "C" void kernel_launch(void* const* d_in, const int* in_sizes, int n_in,
                              void* d_out, int out_size, void* d_ws, size_t ws_size,
                              hipStream_t stream)
{
    const float* x       = (const float*)d_in[0];
    const int*   ei      = (const int*)d_in[1];
    const float* ea      = (const float*)d_in[2];
    const int*   batch   = (const int*)d_in[3];
    const float* skip1_w = (const float*)d_in[4];
    const float* skip1_b = (const float*)d_in[5];
    const float* c1_wl   = (const float*)d_in[6];
    const float* c1_bl   = (const float*)d_in[7];
    const float* c1_wr   = (const float*)d_in[8];
    const float* c1_br   = (const float*)d_in[9];
    const float* c1_we   = (const float*)d_in[10];
    const float* c1_att  = (const float*)d_in[11];
    const float* c1_bias = (const float*)d_in[12];
    const float* bn1_g   = (const float*)d_in[13];
    const float* bn1_b   = (const float*)d_in[14];
    const float* skip2_w = (const float*)d_in[15];
    const float* skip2_b = (const float*)d_in[16];
    const float* c2_wl   = (const float*)d_in[17];
    const float* c2_bl   = (const float*)d_in[18];
    const float* c2_wr   = (const float*)d_in[19];
    const float* c2_br   = (const float*)d_in[20];
    const float* c2_we   = (const float*)d_in[21];
    const float* c2_att  = (const float*)d_in[22];
    const float* c2_bias = (const float*)d_in[23];
    const float* bn2_g   = (const float*)d_in[24];
    const float* bn2_b   = (const float*)d_in[25];
    const float* cls_w   = (const float*)d_in[26];
    const float* cls_b   = (const float*)d_in[27];
    float* outp = (float*)d_out;

    float* ws = (float*)d_ws;
    size_t o = 0;
    float* A   = ws + o; o += 6400000;   // XL1P bf16 [n][128]; layer2: XL2P bf16 (lower) + xr2 fp32 (upper)
    float* B   = ws + o; o += 6400000;   // xr1 fp32 [n][128]
    float* Cb  = ws + o; o += 6400000;   // xp1 fp32 ; later xp2 (lower) + h2 final (upper)
    float* D   = ws + o; o += 6400000;   // h1 pre-BN [n][128] ; later h2 pre-BN [n][64]
    int2*  PAIRS = (int2*)(ws + o); o += 1600000;
    u32*   XP    = (u32*)(ws + o); o += 3200000;   // x packed bf16 [n][64] ; later h packed
    u32*   WT1   = (u32*)(ws + o); o += 24576;     // [384][64]
    u32*   WT2   = (u32*)(ws + o); o += 12288;     // [192][64]
    u32*   COUNTS  = (u32*)(ws + o); o += 50000;
    u32*   CURSORS = (u32*)(ws + o); o += 50000;
    float* STATS1  = ws + o; o += 256;
    float* STATS2  = ws + o; o += 128;
    int*   ROWPTR  = (int*)(ws + o); o += 50016;
    u32*   BSUMS   = (u32*)(ws + o); o += 64;
    float* POOLED  = ws + o; o += 6400;

    u16*   XL1P = (u16*)A;               // [n][128] bf16
    u16*   XL2P = (u16*)A;               // [n][64] bf16 (layer 2)
    float* xr2  = A + 3200000;
    float* xp2  = Cb;
    float* h2   = Cb + 3200000;

    zero_u32_kernel<<<(100384 + 255) / 256, 256, 0, stream>>>(COUNTS, 100384);
    pack_pairs_kernel<<<(NN * 64 + 255) / 256, 256, 0, stream>>>(x, XP, NN * 64);
    wpack3_kernel<<<96, 256, 0, stream>>>(c1_wl, c1_wr, skip1_w, WT1, 128);
    wpack3_kernel<<<48, 256, 0, stream>>>(c2_wl, c2_wr, skip2_w, WT2, 64);

    count_edges_kernel<<<(NE + 255) / 256, 256, 0, stream>>>(ei, COUNTS);
    scan_part1_kernel<<<49, 256, 0, stream>>>(COUNTS, BSUMS);
    scan_offsets_kernel<<<1, 64, 0, stream>>>(BSUMS, 49);
    scan_final_kernel<<<49, 256, 0, stream>>>(COUNTS, BSUMS, ROWPTR);
    scatter_edges_kernel<<<(NE + 255) / 256, 256, 0, stream>>>(ei, ROWPTR, CURSORS, PAIRS);

    // ---- layer 1 ----
    gemm_mfma_kernel<<<dim3(782, 6), 256, 0, stream>>>(XP, WT1,
        XL1P, B, Cb, c1_bl, c1_br, skip1_b, NN, 2, 128);
    gat1_fused_kernel<<<NN / 4, 256, 0, stream>>>((const u32*)XL1P, B, ea, PAIRS, ROWPTR, c1_we, c1_att, c1_bias, D);
    bn_stats_kernel<128><<<98, 256, 0, stream>>>(D, STATS1);
    bn_apply_pack_kernel<<<(NN * 64 + 255) / 256, 256, 0, stream>>>(D, Cb, STATS1, bn1_g, bn1_b, XP);

    // ---- layer 2 ----
    gemm_mfma_kernel<<<dim3(782, 3), 256, 0, stream>>>(XP, WT2,
        XL2P, xr2, xp2, c2_bl, c2_br, skip2_b, NN, 1, 64);
    gat2_fused_kernel<<<NN / 4, 256, 0, stream>>>(XL2P, xr2, ea, PAIRS, ROWPTR, c2_we, c2_att, c2_bias, D);
    bn_stats_kernel<64><<<98, 256, 0, stream>>>(D, STATS2);
    bn_apply_kernel<64><<<(NN * 64 + 255) / 256, 256, 0, stream>>>(D, xp2, STATS2, bn2_g, bn2_b, h2);

    // ---- pool + classify ----
    pool_kernel<<<GG, 256, 0, stream>>>(h2, batch, POOLED);
    classifier_kernel<<<1, 128, 0, stream>>>(POOLED, cls_w, cls_b, outp);
}

// Round 9
// 677.204 us; speedup vs baseline: 1.0579x; 1.0579x over previous
//
#include <hip/hip_runtime.h>
#include <math.h>

#define NN 50000
#define NE 800000
#define GG 50

typedef unsigned int u32;
typedef unsigned short u16;
typedef float v2f __attribute__((ext_vector_type(2)));
typedef short bf16x8 __attribute__((ext_vector_type(8)));
typedef float f32x4 __attribute__((ext_vector_type(4)));

__device__ __forceinline__ float uaf(u32 x) { return __uint_as_float(x); }

__device__ __forceinline__ u32 bfpack2(float x, float y) {
    u32 a = __float_as_uint(x), b = __float_as_uint(y);
    a = (a + 0x7fffu + ((a >> 16) & 1u)) >> 16;
    b = (b + 0x7fffu + ((b >> 16) & 1u)) & 0xffff0000u;
    return b | a;
}
__device__ __forceinline__ u16 bf16of(float x) {
    u32 a = __float_as_uint(x);
    return (u16)((a + 0x7fffu + ((a >> 16) & 1u)) >> 16);
}

// DPP partial reductions (VALU pipe). ctrl must be an immediate.
template <int CTRL>
__device__ __forceinline__ float dpp_add(float v) {
    int t = __builtin_amdgcn_update_dpp(0, __float_as_int(v), CTRL, 0xf, 0xf, true);
    return v + __int_as_float(t);
}
__device__ __forceinline__ float swz_xor16_add(float v) {
    int t = __builtin_amdgcn_ds_swizzle(__float_as_int(v), 0x401F);
    return v + __int_as_float(t);
}
// after RED4+xor16: each 32-group holds its sum; total = group0 + group1 (uniform)
__device__ __forceinline__ float total64(float v) {
    return __int_as_float(__builtin_amdgcn_readlane(__float_as_int(v), 0))
         + __int_as_float(__builtin_amdgcn_readlane(__float_as_int(v), 32));
}
#define RED4_STAGES(q)  do {                                                    \
    _Pragma("unroll") for (int j = 0; j < 4; ++j) q[j] = dpp_add<0xB1>(q[j]);  \
    _Pragma("unroll") for (int j = 0; j < 4; ++j) q[j] = dpp_add<0x4E>(q[j]);  \
    _Pragma("unroll") for (int j = 0; j < 4; ++j) q[j] = dpp_add<0x141>(q[j]); \
    _Pragma("unroll") for (int j = 0; j < 4; ++j) q[j] = dpp_add<0x140>(q[j]); \
} while (0)

// ---------------- utility ----------------
__global__ void zero_u32_kernel(u32* __restrict__ p, int n) {
    int i = blockIdx.x * 256 + threadIdx.x;
    if (i < n) p[i] = 0u;
}

// fp32 pairs -> packed bf16 u32 (generic)
__global__ void pack_pairs_kernel(const float* __restrict__ src, u32* __restrict__ dst, int npairs) {
    int i = blockIdx.x * 256 + threadIdx.x;
    if (i < npairs) {
        float2 v = *(const float2*)(src + (size_t)i * 2);
        dst[i] = bfpack2(v.x, v.y);
    }
}

// 3x W [128][M] fp32 -> Wt [3*M][64] packed bf16 k-pairs (transposed)
__global__ void wpack3_kernel(const float* __restrict__ W0, const float* __restrict__ W1,
                              const float* __restrict__ W2, u32* __restrict__ Wt, int M) {
    int i = blockIdx.x * 256 + threadIdx.x;
    int per = M * 64;
    if (i < 3 * per) {
        int mat = i / per;
        int r = i - mat * per;
        const float* W = (mat == 0) ? W0 : (mat == 1) ? W1 : W2;
        int col = r >> 6, c = r & 63;
        Wt[i] = bfpack2(W[(size_t)(2 * c) * M + col], W[(size_t)(2 * c + 1) * M + col]);
    }
}

// ---------------- CSR build (by dst) ----------------
__global__ void count_edges_kernel(const int* __restrict__ ei, u32* __restrict__ counts) {
    int e = blockIdx.x * 256 + threadIdx.x;
    if (e < NE) atomicAdd(&counts[ei[NE + e]], 1u);
}

__global__ void scan_part1_kernel(const u32* __restrict__ counts, u32* __restrict__ bsums) {
    __shared__ u32 ls[256];
    int t = threadIdx.x;
    int base = blockIdx.x * 1024 + t * 4;
    u32 s = 0;
#pragma unroll
    for (int j = 0; j < 4; ++j) { int idx = base + j; if (idx < NN) s += counts[idx]; }
    ls[t] = s;
    __syncthreads();
    for (int off = 128; off > 0; off >>= 1) {
        if (t < off) ls[t] += ls[t + off];
        __syncthreads();
    }
    if (t == 0) bsums[blockIdx.x] = ls[0];
}

__global__ void scan_offsets_kernel(u32* bsums, int nb) {
    int lane = threadIdx.x;
    u32 v = (lane < nb) ? bsums[lane] : 0u;
#pragma unroll
    for (int off = 1; off < 64; off <<= 1) {
        u32 t = __shfl_up(v, off, 64);
        if (lane >= off) v += t;
    }
    u32 ex = __shfl_up(v, 1, 64);
    if (lane == 0) ex = 0u;
    if (lane < nb) bsums[lane] = ex;
}

__global__ void scan_final_kernel(const u32* __restrict__ counts, const u32* __restrict__ bsums,
                                  int* __restrict__ rowptr) {
    __shared__ u32 ls[256];
    int t = threadIdx.x;
    int base = blockIdx.x * 1024 + t * 4;
    u32 c[4];
    u32 s = 0;
#pragma unroll
    for (int j = 0; j < 4; ++j) { int idx = base + j; c[j] = (idx < NN) ? counts[idx] : 0u; s += c[j]; }
    ls[t] = s;
    __syncthreads();
    for (int off = 1; off < 256; off <<= 1) {
        u32 add = (t >= off) ? ls[t - off] : 0u;
        __syncthreads();
        ls[t] += add;
        __syncthreads();
    }
    u32 run = ls[t] - s + bsums[blockIdx.x];
#pragma unroll
    for (int j = 0; j < 4; ++j) { int idx = base + j; if (idx < NN) { rowptr[idx] = (int)run; } run += c[j]; }
    if (blockIdx.x == 0 && t == 0) rowptr[NN] = NE;
}

__global__ void scatter_edges_kernel(const int* __restrict__ ei, const int* __restrict__ rowptr,
                                     u32* __restrict__ cursors, int2* __restrict__ pairs) {
    int e = blockIdx.x * 256 + threadIdx.x;
    if (e < NE) {
        int src = ei[e];
        int d = ei[NE + e];
        u32 pos = atomicAdd(&cursors[d], 1u);
        pairs[rowptr[d] + pos] = make_int2(src, e);
    }
}

// ---------------- MFMA GEMM: [n,128]bf16 @ Wt -> 3 mats ----------------
__global__ __launch_bounds__(256) void gemm_mfma_kernel(
    const u32* __restrict__ Xp, const u32* __restrict__ Wt,
    u16* __restrict__ out0, float* __restrict__ out1, float* __restrict__ out2,
    const float* __restrict__ b0, const float* __restrict__ b1, const float* __restrict__ b2,
    int n, int nbPerMat, int outStride)
{
    __shared__ __align__(16) u32 Xs[64 * 68];
    __shared__ __align__(16) u32 Ws[64 * 68];
    int t = threadIdx.x;
    int row0 = blockIdx.x * 64;
    int nb = blockIdx.y;
    int mat = nb / nbPerMat;
    int col0 = (nb - mat * nbPerMat) * 64;
    int gcol0 = nb * 64;

#pragma unroll
    for (int i = 0; i < 16; ++i) {
        int flat = t + 256 * i;
        int r = flat >> 6, c = flat & 63;
        int gr = row0 + r;
        u32 v = (gr < n) ? Xp[(size_t)gr * 64 + c] : 0u;
        Xs[r * 68 + c] = v;
    }
#pragma unroll
    for (int i = 0; i < 16; ++i) {
        int flat = t + 256 * i;
        int cc = flat >> 6, c = flat & 63;
        Ws[cc * 68 + c] = Wt[(size_t)(gcol0 + cc) * 64 + c];
    }
    __syncthreads();

    int w = t >> 6, lane = t & 63;
    int l15 = lane & 15, quad = lane >> 4;
    f32x4 acc[4] = {};
#pragma unroll
    for (int kk = 0; kk < 4; ++kk) {
        bf16x8 af = *(const bf16x8*)&Xs[(w * 16 + l15) * 68 + kk * 16 + quad * 4];
#pragma unroll
        for (int j = 0; j < 4; ++j) {
            bf16x8 bf = *(const bf16x8*)&Ws[(j * 16 + l15) * 68 + kk * 16 + quad * 4];
            acc[j] = __builtin_amdgcn_mfma_f32_16x16x32_bf16(af, bf, acc[j], 0, 0, 0);
        }
    }

    const float* bp = (mat == 0) ? b0 : (mat == 1) ? b1 : b2;
#pragma unroll
    for (int j = 0; j < 4; ++j) {
        int col = col0 + j * 16 + l15;
        float bb = bp[col];
#pragma unroll
        for (int r = 0; r < 4; ++r) {
            int grow = row0 + w * 16 + quad * 4 + r;
            if (grow < n) {
                float v = acc[j][r] + bb;
                if (mat == 0) {
                    out0[(size_t)grow * outStride + col] = bf16of(v);
                } else if (mat == 1) {
                    out1[(size_t)grow * outStride + col] = v;
                } else {
                    out2[(size_t)grow * outStride + col] = v;
                }
            }
        }
    }
}

// ---------------- fused GATv2 layer 1 (H=2, C=64): bf16 xl+ea, DPP reduce, no-max softmax ----------------
__global__ __launch_bounds__(256) void gat1_fused_kernel(
    const u32* __restrict__ xlp, const float* __restrict__ xr,
    const u32* __restrict__ eah, const int2* __restrict__ pairs,
    const int* __restrict__ rowptr, const float* __restrict__ We,
    const float* __restrict__ att, const float* __restrict__ bias,
    float* __restrict__ out)
{
    int lane = threadIdx.x & 63;
    int d = (blockIdx.x * 256 + threadIdx.x) >> 6;
    if (d >= NN) return;
    int du = __builtin_amdgcn_readfirstlane(d);
    int beg = rowptr[du], end = rowptr[du + 1];
    int c0 = lane * 2;
    v2f w[16];
#pragma unroll
    for (int k = 0; k < 16; ++k) {
        float2 t2 = *(const float2*)(We + k * 128 + c0);
        w[k] = (v2f){t2.x, t2.y};
    }
    float a0 = att[c0], a1 = att[c0 + 1];
    float2 bt = *(const float2*)(bias + c0);
    float2 xq = *(const float2*)(xr + (size_t)du * 128 + c0);
    v2f xrv = {xq.x, xq.y};

    float s = 0.f;
    v2f acc = {0.f, 0.f};

    int cnt = (end - beg) >> 2;
    int2 pA[4]; u32 eA[4][8]; u32 xA[4];
    int2 pB[4]; u32 eB[4][8]; u32 xB[4];

#define G1_LOAD(P, EB, X, base_) do {                                          \
    _Pragma("unroll")                                                          \
    for (int j = 0; j < 4; ++j) P[j] = pairs[(base_) + j];                     \
    _Pragma("unroll")                                                          \
    for (int j = 0; j < 4; ++j) {                                              \
        const u32* er_ = eah + (size_t)P[j].y * 8;                             \
        _Pragma("unroll")                                                      \
        for (int k = 0; k < 8; ++k) EB[j][k] = er_[k];                         \
        X[j] = xlp[(size_t)P[j].x * 64 + lane];                                \
    }                                                                          \
} while (0)

#define G1_PROC(EB, X) do {                                                    \
    float q[4]; v2f xv[4];                                                     \
    _Pragma("unroll")                                                          \
    for (int j = 0; j < 4; ++j) {                                              \
        v2f e = {0.f, 0.f};                                                    \
        _Pragma("unroll")                                                      \
        for (int kk = 0; kk < 8; ++kk) {                                       \
            u32 pk = EB[j][kk];                                                \
            e = w[2 * kk] * uaf(pk << 16) + e;                                 \
            e = w[2 * kk + 1] * uaf(pk & 0xffff0000u) + e;                     \
        }                                                                      \
        u32 px = X[j];                                                         \
        xv[j] = (v2f){uaf(px << 16), uaf(px & 0xffff0000u)};                   \
        v2f mm = xv[j] + xrv + e;                                              \
        float lx = fmaxf(mm.x, 0.2f * mm.x);                                   \
        float ly = fmaxf(mm.y, 0.2f * mm.y);                                   \
        q[j] = fmaf(lx, a0, ly * a1);                                          \
    }                                                                          \
    RED4_STAGES(q);                                                            \
    _Pragma("unroll")                                                          \
    for (int j = 0; j < 4; ++j) q[j] = swz_xor16_add(q[j]);                    \
    float w0 = __expf(q[0]), w1 = __expf(q[1]);                                \
    float w2 = __expf(q[2]), w3 = __expf(q[3]);                                \
    s += (w0 + w1) + (w2 + w3);                                                \
    acc = acc + (xv[0] * w0 + xv[1] * w1) + (xv[2] * w2 + xv[3] * w3);         \
} while (0)

    if (cnt > 0) {
        G1_LOAD(pA, eA, xA, beg);
        int g = 0;
        for (; g + 2 <= cnt; g += 2) {
            G1_LOAD(pB, eB, xB, beg + (g + 1) * 4);
            G1_PROC(eA, xA);
            if (g + 2 < cnt) G1_LOAD(pA, eA, xA, beg + (g + 2) * 4);
            G1_PROC(eB, xB);
        }
        if (g < cnt) G1_PROC(eA, xA);
    }
#undef G1_LOAD
#undef G1_PROC
    for (int i = beg + cnt * 4; i < end; ++i) {
        int2 pr = pairs[i];
        const u32* er = eah + (size_t)pr.y * 8;
        u32 px = xlp[(size_t)pr.x * 64 + lane];
        v2f xv = {uaf(px << 16), uaf(px & 0xffff0000u)};
        v2f e = {0.f, 0.f};
#pragma unroll
        for (int kk = 0; kk < 8; ++kk) {
            u32 pk = er[kk];
            e = w[2 * kk] * uaf(pk << 16) + e;
            e = w[2 * kk + 1] * uaf(pk & 0xffff0000u) + e;
        }
        v2f mm = xv + xrv + e;
        float lx = fmaxf(mm.x, 0.2f * mm.x);
        float ly = fmaxf(mm.y, 0.2f * mm.y);
        float p = fmaf(lx, a0, ly * a1);
        p = dpp_add<0xB1>(p);
        p = dpp_add<0x4E>(p);
        p = dpp_add<0x141>(p);
        p = dpp_add<0x140>(p);
        p = swz_xor16_add(p);
        float ww = __expf(p);
        s += ww;
        acc = acc + xv * ww;
    }
    float inv = 1.f / (s + 1e-16f);
    float2 o;
    o.x = fmaf(acc.x, inv, bt.x);
    o.y = fmaf(acc.y, inv, bt.y);
    *(float2*)(out + (size_t)d * 128 + c0) = o;
}

// ---------------- fused GATv2 layer 2 (H=1, C=64): bf16 xl+ea, DPP reduce, no-max softmax ----------------
__global__ __launch_bounds__(256) void gat2_fused_kernel(
    const u16* __restrict__ xlp, const float* __restrict__ xr,
    const u32* __restrict__ eah, const int2* __restrict__ pairs,
    const int* __restrict__ rowptr, const float* __restrict__ We,
    const float* __restrict__ att, const float* __restrict__ bias,
    float* __restrict__ out)
{
    int lane = threadIdx.x & 63;
    int d = (blockIdx.x * 256 + threadIdx.x) >> 6;
    if (d >= NN) return;
    int du = __builtin_amdgcn_readfirstlane(d);
    int beg = rowptr[du], end = rowptr[du + 1];
    float w[16];
#pragma unroll
    for (int k = 0; k < 16; ++k) w[k] = We[k * 64 + lane];
    float a0 = att[lane];
    float bb = bias[lane];
    float xrv = xr[(size_t)du * 64 + lane];

    float s = 0.f, acc = 0.f;

    int cnt = (end - beg) >> 2;
    int2 pA[4]; u32 eA[4][8]; float xA[4];
    int2 pB[4]; u32 eB[4][8]; float xB[4];

#define G2_LOAD(P, EB, X, base_) do {                                          \
    _Pragma("unroll")                                                          \
    for (int j = 0; j < 4; ++j) P[j] = pairs[(base_) + j];                     \
    _Pragma("unroll")                                                          \
    for (int j = 0; j < 4; ++j) {                                              \
        const u32* er_ = eah + (size_t)P[j].y * 8;                             \
        _Pragma("unroll")                                                      \
        for (int k = 0; k < 8; ++k) EB[j][k] = er_[k];                         \
        X[j] = uaf((u32)xlp[(size_t)P[j].x * 64 + lane] << 16);                \
    }                                                                          \
} while (0)

#define G2_PROC(EB, X) do {                                                    \
    float q[4];                                                                \
    _Pragma("unroll")                                                          \
    for (int j = 0; j < 4; ++j) {                                              \
        float e = 0.f;                                                         \
        _Pragma("unroll")                                                      \
        for (int kk = 0; kk < 8; ++kk) {                                       \
            u32 pk = EB[j][kk];                                                \
            e = fmaf(uaf(pk << 16), w[2 * kk], e);                             \
            e = fmaf(uaf(pk & 0xffff0000u), w[2 * kk + 1], e);                 \
        }                                                                      \
        float mm = X[j] + xrv + e;                                             \
        mm = fmaxf(mm, 0.2f * mm);                                             \
        q[j] = mm * a0;                                                        \
    }                                                                          \
    RED4_STAGES(q);                                                            \
    _Pragma("unroll")                                                          \
    for (int j = 0; j < 4; ++j) { q[j] = swz_xor16_add(q[j]); q[j] = total64(q[j]); } \
    float w0 = __expf(q[0]), w1 = __expf(q[1]);                                \
    float w2 = __expf(q[2]), w3 = __expf(q[3]);                                \
    s += (w0 + w1) + (w2 + w3);                                                \
    acc += fmaf(w0, X[0], fmaf(w1, X[1], fmaf(w2, X[2], w3 * X[3])));          \
} while (0)

    if (cnt > 0) {
        G2_LOAD(pA, eA, xA, beg);
        int g = 0;
        for (; g + 2 <= cnt; g += 2) {
            G2_LOAD(pB, eB, xB, beg + (g + 1) * 4);
            G2_PROC(eA, xA);
            if (g + 2 < cnt) G2_LOAD(pA, eA, xA, beg + (g + 2) * 4);
            G2_PROC(eB, xB);
        }
        if (g < cnt) G2_PROC(eA, xA);
    }
#undef G2_LOAD
#undef G2_PROC
    for (int i = beg + cnt * 4; i < end; ++i) {
        int2 pr = pairs[i];
        const u32* er = eah + (size_t)pr.y * 8;
        float xv = uaf((u32)xlp[(size_t)pr.x * 64 + lane] << 16);
        float e = 0.f;
#pragma unroll
        for (int kk = 0; kk < 8; ++kk) {
            u32 pk = er[kk];
            e = fmaf(uaf(pk << 16), w[2 * kk], e);
            e = fmaf(uaf(pk & 0xffff0000u), w[2 * kk + 1], e);
        }
        float mm = xv + xrv + e;
        mm = fmaxf(mm, 0.2f * mm);
        float p = mm * a0;
        p = dpp_add<0xB1>(p);
        p = dpp_add<0x4E>(p);
        p = dpp_add<0x141>(p);
        p = dpp_add<0x140>(p);
        p = swz_xor16_add(p);
        p = total64(p);
        float ww = __expf(p);
        s += ww;
        acc = fmaf(ww, xv, acc);
    }
    out[(size_t)d * 64 + lane] = acc / (s + 1e-16f) + bb;
}

// ---------------- batch-norm stats ----------------
template <int C>
__global__ __launch_bounds__(256) void bn_stats_kernel(const float* __restrict__ h, float* __restrict__ stats) {
    const int SUB = 256 / C;
    int t = threadIdx.x;
    int c = t & (C - 1);
    int rs = t / C;
    int r0 = blockIdx.x * 512;
    int r1 = min(NN, r0 + 512);
    float s = 0.f, s2 = 0.f;
    for (int r = r0 + rs; r < r1; r += SUB) {
        float v = h[(size_t)r * C + c];
        s += v; s2 = fmaf(v, v, s2);
    }
    __shared__ float ls[256], ls2[256];
    ls[t] = s; ls2[t] = s2;
    __syncthreads();
    if (rs == 0) {
        for (int j = 1; j < SUB; ++j) { s += ls[j * C + c]; s2 += ls2[j * C + c]; }
        atomicAdd(&stats[c], s);
        atomicAdd(&stats[C + c], s2);
    }
}

// ---------------- BN apply + skip + ELU -> packed bf16 ----------------
__global__ __launch_bounds__(256) void bn_apply_pack_kernel(
    const float* __restrict__ h, const float* __restrict__ xp,
    const float* __restrict__ stats, const float* __restrict__ g,
    const float* __restrict__ b, u32* __restrict__ outp)
{
    int i = blockIdx.x * 256 + threadIdx.x;
    if (i >= NN * 64) return;
    int c2 = i & 63;
    int row = i >> 6;
    int c = c2 * 2;
    float2 hv = *(const float2*)(h + (size_t)row * 128 + c);
    float2 xv = *(const float2*)(xp + (size_t)row * 128 + c);
    float mu0 = stats[c] * (1.f / NN);
    float var0 = stats[128 + c] * (1.f / NN) - mu0 * mu0;
    float v0 = (hv.x - mu0) * rsqrtf(var0 + 1e-5f) * g[c] + b[c] + xv.x;
    v0 = (v0 > 0.f) ? v0 : expm1f(v0);
    float mu1 = stats[c + 1] * (1.f / NN);
    float var1 = stats[129 + c] * (1.f / NN) - mu1 * mu1;
    float v1 = (hv.y - mu1) * rsqrtf(var1 + 1e-5f) * g[c + 1] + b[c + 1] + xv.y;
    v1 = (v1 > 0.f) ? v1 : expm1f(v1);
    outp[i] = bfpack2(v0, v1);
}

// ---------------- BN apply + skip + ELU (fp32 out, final layer) ----------------
template <int C>
__global__ __launch_bounds__(256) void bn_apply_kernel(
    const float* __restrict__ h, const float* __restrict__ xp,
    const float* __restrict__ stats, const float* __restrict__ g,
    const float* __restrict__ b, float* __restrict__ outp)
{
    int i = blockIdx.x * 256 + threadIdx.x;
    if (i >= NN * C) return;
    int c = i & (C - 1);
    float mu = stats[c] * (1.f / NN);
    float var = stats[C + c] * (1.f / NN) - mu * mu;
    float sc = rsqrtf(var + 1e-5f) * g[c];
    float v = (h[i] - mu) * sc + b[c] + xp[i];
    outp[i] = (v > 0.f) ? v : expm1f(v);
}

// ---------------- per-graph mean/max pooling ----------------
__global__ __launch_bounds__(256) void pool_kernel(
    const float* __restrict__ h2, const int* __restrict__ batch, float* __restrict__ pooled)
{
    int g = blockIdx.x;
    int t = threadIdx.x;
    int lane = t & 63, w = t >> 6;
    int lo = 0, hi = NN;
    while (lo < hi) { int mid = (lo + hi) >> 1; if (batch[mid] < g) lo = mid + 1; else hi = mid; }
    int s0 = lo;
    hi = NN;
    while (lo < hi) { int mid = (lo + hi) >> 1; if (batch[mid] < g + 1) lo = mid + 1; else hi = mid; }
    int e0 = lo;
    float sum = 0.f, mx = -INFINITY;
    for (int r = s0 + w; r < e0; r += 4) {
        float v = h2[(size_t)r * 64 + lane];
        sum += v; mx = fmaxf(mx, v);
    }
    __shared__ float lsum[256], lmax[256];
    lsum[t] = sum; lmax[t] = mx;
    __syncthreads();
    if (w == 0) {
        for (int j = 1; j < 4; ++j) { sum += lsum[j * 64 + lane]; mx = fmaxf(mx, lmax[j * 64 + lane]); }
        float cnt = (float)(e0 - s0);
        pooled[g * 128 + lane] = sum / fmaxf(cnt, 1.f);
        pooled[g * 128 + 64 + lane] = mx;
    }
}

// ---------------- classifier ----------------
__global__ void classifier_kernel(const float* __restrict__ pooled, const float* __restrict__ w,
                                  const float* __restrict__ b, float* __restrict__ outp)
{
    int t = threadIdx.x;
    if (t < 100) {
        int g = t >> 1, c = t & 1;
        float acc = b[c];
        for (int k = 0; k < 128; ++k) acc = fmaf(pooled[g * 128 + k], w[k * 2 + c], acc);
        outp[t] = acc;
    }
}

extern "C" void kernel_launch(void* const* d_in, const int* in_sizes, int n_in,
                              void* d_out, int out_size, void* d_ws, size_t ws_size,
                              hipStream_t stream)
{
    const float* x       = (const float*)d_in[0];
    const int*   ei      = (const int*)d_in[1];
    const float* ea      = (const float*)d_in[2];
    const int*   batch   = (const int*)d_in[3];
    const float* skip1_w = (const float*)d_in[4];
    const float* skip1_b = (const float*)d_in[5];
    const float* c1_wl   = (const float*)d_in[6];
    const float* c1_bl   = (const float*)d_in[7];
    const float* c1_wr   = (const float*)d_in[8];
    const float* c1_br   = (const float*)d_in[9];
    const float* c1_we   = (const float*)d_in[10];
    const float* c1_att  = (const float*)d_in[11];
    const float* c1_bias = (const float*)d_in[12];
    const float* bn1_g   = (const float*)d_in[13];
    const float* bn1_b   = (const float*)d_in[14];
    const float* skip2_w = (const float*)d_in[15];
    const float* skip2_b = (const float*)d_in[16];
    const float* c2_wl   = (const float*)d_in[17];
    const float* c2_bl   = (const float*)d_in[18];
    const float* c2_wr   = (const float*)d_in[19];
    const float* c2_br   = (const float*)d_in[20];
    const float* c2_we   = (const float*)d_in[21];
    const float* c2_att  = (const float*)d_in[22];
    const float* c2_bias = (const float*)d_in[23];
    const float* bn2_g   = (const float*)d_in[24];
    const float* bn2_b   = (const float*)d_in[25];
    const float* cls_w   = (const float*)d_in[26];
    const float* cls_b   = (const float*)d_in[27];
    float* outp = (float*)d_out;

    float* ws = (float*)d_ws;
    size_t o = 0;
    float* A   = ws + o; o += 6400000;   // XL1P bf16 [n][128]; layer2: XL2P bf16 (lower) + xr2 fp32 (upper)
    float* B   = ws + o; o += 6400000;   // xr1 fp32 [n][128]
    float* Cb  = ws + o; o += 6400000;   // xp1 fp32 ; later xp2 (lower) + h2 final (upper)
    float* D   = ws + o; o += 6400000;   // h1 pre-BN [n][128] ; later h2 pre-BN [n][64]
    int2*  PAIRS = (int2*)(ws + o); o += 1600000;
    u32*   EAH   = (u32*)(ws + o); o += 6400000;   // ea packed bf16 [E][8]
    u32*   XP    = (u32*)(ws + o); o += 3200000;   // x packed bf16 [n][64] ; later h packed
    u32*   WT1   = (u32*)(ws + o); o += 24576;     // [384][64]
    u32*   WT2   = (u32*)(ws + o); o += 12288;     // [192][64]
    u32*   COUNTS  = (u32*)(ws + o); o += 50000;
    u32*   CURSORS = (u32*)(ws + o); o += 50000;
    float* STATS1  = ws + o; o += 256;
    float* STATS2  = ws + o; o += 128;
    int*   ROWPTR  = (int*)(ws + o); o += 50016;
    u32*   BSUMS   = (u32*)(ws + o); o += 64;
    float* POOLED  = ws + o; o += 6400;

    u16*   XL1P = (u16*)A;               // [n][128] bf16
    u16*   XL2P = (u16*)A;               // [n][64] bf16 (layer 2)
    float* xr2  = A + 3200000;
    float* xp2  = Cb;
    float* h2   = Cb + 3200000;

    zero_u32_kernel<<<(100384 + 255) / 256, 256, 0, stream>>>(COUNTS, 100384);
    pack_pairs_kernel<<<(NE * 8 + 255) / 256, 256, 0, stream>>>(ea, EAH, NE * 8);
    pack_pairs_kernel<<<(NN * 64 + 255) / 256, 256, 0, stream>>>(x, XP, NN * 64);
    wpack3_kernel<<<96, 256, 0, stream>>>(c1_wl, c1_wr, skip1_w, WT1, 128);
    wpack3_kernel<<<48, 256, 0, stream>>>(c2_wl, c2_wr, skip2_w, WT2, 64);

    count_edges_kernel<<<(NE + 255) / 256, 256, 0, stream>>>(ei, COUNTS);
    scan_part1_kernel<<<49, 256, 0, stream>>>(COUNTS, BSUMS);
    scan_offsets_kernel<<<1, 64, 0, stream>>>(BSUMS, 49);
    scan_final_kernel<<<49, 256, 0, stream>>>(COUNTS, BSUMS, ROWPTR);
    scatter_edges_kernel<<<(NE + 255) / 256, 256, 0, stream>>>(ei, ROWPTR, CURSORS, PAIRS);

    // ---- layer 1 ----
    gemm_mfma_kernel<<<dim3(782, 6), 256, 0, stream>>>(XP, WT1,
        XL1P, B, Cb, c1_bl, c1_br, skip1_b, NN, 2, 128);
    gat1_fused_kernel<<<NN / 4, 256, 0, stream>>>((const u32*)XL1P, B, EAH, PAIRS, ROWPTR, c1_we, c1_att, c1_bias, D);
    bn_stats_kernel<128><<<98, 256, 0, stream>>>(D, STATS1);
    bn_apply_pack_kernel<<<(NN * 64 + 255) / 256, 256, 0, stream>>>(D, Cb, STATS1, bn1_g, bn1_b, XP);

    // ---- layer 2 ----
    gemm_mfma_kernel<<<dim3(782, 3), 256, 0, stream>>>(XP, WT2,
        XL2P, xr2, xp2, c2_bl, c2_br, skip2_b, NN, 1, 64);
    gat2_fused_kernel<<<NN / 4, 256, 0, stream>>>(XL2P, xr2, EAH, PAIRS, ROWPTR, c2_we, c2_att, c2_bias, D);
    bn_stats_kernel<64><<<98, 256, 0, stream>>>(D, STATS2);
    bn_apply_kernel<64><<<(NN * 64 + 255) / 256, 256, 0, stream>>>(D, xp2, STATS2, bn2_g, bn2_b, h2);

    // ---- pool + classify ----
    pool_kernel<<<GG, 256, 0, stream>>>(h2, batch, POOLED);
    classifier_kernel<<<1, 128, 0, stream>>>(POOLED, cls_w, cls_b, outp);
}